// Round 5
// baseline (646.308 us; speedup 1.0000x reference)
//
#include <hip/hip_runtime.h>
#include <hip/hip_bf16.h>
#include <cstdint>
#include <cstddef>

#define N_NODES 5000
#define DIN 512
#define DOUT 16
#define KMP 3
#define NCLS 100
#define WSTRIDE 160   // u32 words per bit-row (157 used, padded)
#define NWORDS 157    // ceil(5000/32)
#define NQ 1250       // float4 groups per row
#define CAPK 160      // per-plane neighbor list capacity (deg ~64±8)
#define CAPU 320      // union list capacity (deg ~189±14)

// ---- K1: adj -> bit planes + degree rsqrt + per-plane neighbor lists ------
__global__ void k1_bits_deg_nbr(const float* __restrict__ adj,
                                uint32_t* __restrict__ planes,
                                float* __restrict__ dinv,
                                uint16_t* __restrict__ nbrK,
                                int* __restrict__ cntK) {
    int row = blockIdx.x;
    int t   = threadIdx.x;
    int lane = t & 63;
    int wv   = t >> 6;
    const float* arow = adj + (size_t)row * N_NODES;
    __shared__ uint32_t nib32[320];       // 1280 nibble bytes
    __shared__ int wtot[4];
    uint8_t* nib = (uint8_t*)nib32;
    #pragma unroll
    for (int it = 0; it < 5; ++it) {
        int q = it * 256 + t;             // q < 1280
        uint32_t m = 0;
        if (q < NQ) {
            float4 v = *(const float4*)(arow + 4 * q);
            m = (v.x != 0.f ? 1u : 0u) | (v.y != 0.f ? 2u : 0u) |
                (v.z != 0.f ? 4u : 0u) | (v.w != 0.f ? 8u : 0u);
        }
        nib[q] = (uint8_t)m;
    }
    __syncthreads();
    uint32_t word = 0;
    int cnt = 0;
    if (t < NWORDS) {
        uint32_t lo = nib32[2 * t], hi = nib32[2 * t + 1];
        word = (lo & 0xFu) | ((lo >> 4) & 0xF0u) | ((lo >> 8) & 0xF00u) | ((lo >> 12) & 0xF000u)
             | ((hi << 16) & 0xF0000u) | ((hi << 12) & 0xF00000u)
             | ((hi << 8) & 0xF000000u) | ((hi << 4) & 0xF0000000u);
        planes[(size_t)row * WSTRIDE + t] = word;
        cnt = __popc(word);
    }
    int x = cnt;
    #pragma unroll
    for (int s = 1; s < 64; s <<= 1) {
        int y = __shfl_up(x, s);
        if (lane >= s) x += y;
    }
    if (lane == 63) wtot[wv] = x;
    __syncthreads();
    int prefix = 0;
    #pragma unroll
    for (int w = 0; w < 4; ++w) if (w < wv) prefix += wtot[w];
    int total = wtot[0] + wtot[1] + wtot[2] + wtot[3];
    int pos = prefix + x - cnt;
    uint16_t* out = nbrK + (size_t)row * CAPK;
    while (word) {
        int b = __builtin_ctz(word);
        word &= word - 1;
        if (pos < CAPK) out[pos] = (uint16_t)(32 * t + b);
        ++pos;
    }
    if (t == 0) {
        dinv[row] = rsqrtf(1.0f + (float)total);
        cntK[row] = (total < CAPK) ? total : CAPK;
    }
}

// ------- K1b: union degree only -> udinv (wave per row) --------------------
__global__ void k_udinv(const uint32_t* __restrict__ planes, float* __restrict__ udinv) {
    int i = blockIdx.x;
    int lane = threadIdx.x;  // 64
    const uint32_t* p0 = planes + (size_t)i * WSTRIDE;
    const uint32_t* p1 = planes + (size_t)(N_NODES + i) * WSTRIDE;
    const uint32_t* p2 = planes + (size_t)(2 * N_NODES + i) * WSTRIDE;
    int cnt = __popc(p0[lane] | p1[lane] | p2[lane])
            + __popc(p0[lane + 64] | p1[lane + 64] | p2[lane + 64]);
    if (lane + 128 < NWORDS)
        cnt += __popc(p0[lane + 128] | p1[lane + 128] | p2[lane + 128]);
    #pragma unroll
    for (int s = 32; s; s >>= 1) cnt += __shfl_xor(cnt, s);
    if (lane == 0) udinv[i] = rsqrtf(1.0f + (float)cnt);
}

// ---------------- K2a: transpose W_gnn -> Wt[k][o][d] ----------------
__global__ void k2a_wt(const float* __restrict__ W, float* __restrict__ Wt) {
    int t = blockIdx.x * blockDim.x + threadIdx.x;
    if (t >= KMP * DIN * DOUT) return;
    int d = t % DIN; int rest = t / DIN; int o = rest % DOUT; int k = rest / DOUT;
    Wt[t] = W[((size_t)k * DIN + d) * DOUT + o];
}

// -------- K2b: XWd[k][j][o] = dinv[k][j]*(feat[j].Wt[k][o]), k folded ------
__global__ void k2b_xwd(const float* __restrict__ feat, const float* __restrict__ Wt,
                        const float* __restrict__ dinv, float* __restrict__ XWd) {
    int t = blockIdx.x * blockDim.x + threadIdx.x;
    if (t >= N_NODES * DOUT) return;
    int o = t & 15; int j = t >> 4;
    const float4* f4 = (const float4*)(feat + (size_t)j * DIN);
    const float4* w0 = (const float4*)(Wt + (size_t)(0 * DOUT + o) * DIN);
    const float4* w1 = (const float4*)(Wt + (size_t)(1 * DOUT + o) * DIN);
    const float4* w2 = (const float4*)(Wt + (size_t)(2 * DOUT + o) * DIN);
    float a0 = 0.f, a1 = 0.f, a2 = 0.f;
    #pragma unroll 2
    for (int d4 = 0; d4 < DIN / 4; ++d4) {
        float4 f = f4[d4];
        float4 b0 = w0[d4], b1 = w1[d4], b2 = w2[d4];
        a0 += f.x * b0.x + f.y * b0.y + f.z * b0.z + f.w * b0.w;
        a1 += f.x * b1.x + f.y * b1.y + f.z * b1.z + f.w * b1.w;
        a2 += f.x * b2.x + f.y * b2.y + f.z * b2.z + f.w * b2.w;
    }
    XWd[(size_t)(0 * N_NODES + j) * DOUT + o] = a0 * dinv[0 * N_NODES + j];
    XWd[(size_t)(1 * N_NODES + j) * DOUT + o] = a1 * dinv[1 * N_NODES + j];
    XWd[(size_t)(2 * N_NODES + j) * DOUT + o] = a2 * dinv[2 * N_NODES + j];
}

// ---- K34: sparse h + max -> f_meta, attention coeffs a4/b4, and Gd --------
__global__ void k34_fmeta_ab_gd(const uint16_t* __restrict__ nbrK, const int* __restrict__ cntK,
                                const float* __restrict__ XWd, const float* __restrict__ dinv,
                                const float* __restrict__ bg, const float* __restrict__ aw,
                                const float* __restrict__ Wf, const float* __restrict__ udinv,
                                float* __restrict__ f_meta, float* __restrict__ a4,
                                float* __restrict__ b4, float* __restrict__ Gd) {
    int t = threadIdx.x;
    int o = t & 15;
    int r = t >> 4;                 // group 0..3
    int i = blockIdx.x * 4 + r;
    __shared__ float fs[4][17];
    float hmax = -1e30f;
    #pragma unroll
    for (int k = 0; k < KMP; ++k) {
        const float* xw = XWd + (size_t)k * N_NODES * DOUT;
        int row = k * N_NODES + i;
        int nn = cntK[row];
        const uint16_t* nb = nbrK + (size_t)row * CAPK;
        float a0 = xw[i * DOUT + o];   // self-loop (diag double-count matches Ahat)
        float a1 = 0.f, a2 = 0.f, a3 = 0.f;
        int n = 0;
        for (; n + 4 <= nn; n += 4) {
            ushort4 jj = *(const ushort4*)(nb + n);
            a0 += xw[(int)jj.x * DOUT + o];
            a1 += xw[(int)jj.y * DOUT + o];
            a2 += xw[(int)jj.z * DOUT + o];
            a3 += xw[(int)jj.w * DOUT + o];
        }
        for (; n < nn; ++n) a0 += xw[(int)nb[n] * DOUT + o];
        float h = dinv[row] * ((a0 + a1) + (a2 + a3)) + bg[k * DOUT + o];
        hmax = fmaxf(hmax, h);
    }
    f_meta[i * DOUT + o] = hmax;
    fs[r][o] = hmax;
    float sa0 = hmax * aw[0 * 32 + o], sb0 = hmax * aw[0 * 32 + 16 + o];
    float sa1 = hmax * aw[1 * 32 + o], sb1 = hmax * aw[1 * 32 + 16 + o];
    float sa2 = hmax * aw[2 * 32 + o], sb2 = hmax * aw[2 * 32 + 16 + o];
    #pragma unroll
    for (int s = 1; s < 16; s <<= 1) {
        sa0 += __shfl_xor(sa0, s, 16); sb0 += __shfl_xor(sb0, s, 16);
        sa1 += __shfl_xor(sa1, s, 16); sb1 += __shfl_xor(sb1, s, 16);
        sa2 += __shfl_xor(sa2, s, 16); sb2 += __shfl_xor(sb2, s, 16);
    }
    if (o < 4) {
        float sa = (o == 0) ? sa0 : (o == 1) ? sa1 : (o == 2) ? sa2 : 0.f;
        float sb = (o == 0) ? sb0 : (o == 1) ? sb1 : (o == 2) ? sb2 : 0.f;
        a4[i * 4 + o] = sa;
        b4[i * 4 + o] = sb;
    }
    __syncthreads();
    float f[DOUT];
    #pragma unroll
    for (int q = 0; q < DOUT; ++q) f[q] = fs[r][q];
    float ud = udinv[i];
    for (int c = o; c < NCLS; c += 16) {
        float acc = 0.f;
        #pragma unroll
        for (int q = 0; q < DOUT; ++q) acc += f[q] * Wf[q * NCLS + c];
        Gd[(size_t)i * NCLS + c] = acc * ud;
    }
}

// ---- K58: fused A_meta emission + predictions, 8 rows/block ---------------
__device__ __forceinline__ float attn_frac(float x0, float x1, float x2,
                                           uint32_t b0, uint32_t b1, uint32_t b2) {
    float e0 = __expf(fmaxf(x0, 0.f));
    float e1 = __expf(fmaxf(x1, 0.f));
    float e2 = __expf(fmaxf(x2, 0.f));
    float num = (b0 ? e0 : 0.f) + (b1 ? e1 : 0.f) + (b2 ? e2 : 0.f);
    return __fdividef(num, e0 + e1 + e2);
}

__global__ __launch_bounds__(256) void k58_ameta_pred(
        const uint32_t* __restrict__ planes, const float* __restrict__ a4,
        const float* __restrict__ b4, const float* __restrict__ Gd,
        const float* __restrict__ udinv, const float* __restrict__ bf,
        float* __restrict__ Am, float* __restrict__ pred) {
    int i0 = blockIdx.x * 8;
    int t = threadIdx.x;
    __shared__ uint32_t pw[3][8][WSTRIDE];   // 15360 B
    __shared__ uint16_t ulist[8][CAPU];      // 5120 B
    __shared__ int ucnt[8];
    __shared__ float a_s[8][3];
    // Stage A: planes -> LDS (3*8*157 words)
    for (int idx = t; idx < 3 * 8 * NWORDS; idx += 256) {
        int w = idx % NWORDS; int rr = (idx / NWORDS) & 7; int p = idx / (NWORDS * 8);
        pw[p][rr][w] = planes[(size_t)(p * N_NODES + i0 + rr) * WSTRIDE + w];
    }
    if (t < 24) { int r = t / 3, k = t % 3; a_s[r][k] = a4[(i0 + r) * 4 + k]; }
    __syncthreads();
    // union lists from LDS: wave wv does rows 2wv, 2wv+1
    int wv = t >> 6, lane = t & 63;
    for (int rr = 2 * wv; rr < 2 * wv + 2; ++rr) {
        uint32_t w0 = pw[0][rr][lane] | pw[1][rr][lane] | pw[2][rr][lane];
        uint32_t w1 = pw[0][rr][lane + 64] | pw[1][rr][lane + 64] | pw[2][rr][lane + 64];
        uint32_t w2 = 0;
        if (lane + 128 < NWORDS)
            w2 = pw[0][rr][lane + 128] | pw[1][rr][lane + 128] | pw[2][rr][lane + 128];
        int cnt = __popc(w0) + __popc(w1) + __popc(w2);
        int x = cnt;
        #pragma unroll
        for (int s = 1; s < 64; s <<= 1) {
            int y = __shfl_up(x, s);
            if (lane >= s) x += y;
        }
        int pos = x - cnt;
        int total = __shfl(x, 63);
        uint32_t wsr[3] = {w0, w1, w2};
        #pragma unroll
        for (int p = 0; p < 3; ++p) {
            uint32_t word = wsr[p];
            int base = 32 * (lane + 64 * p);
            while (word) {
                int b = __builtin_ctz(word);
                word &= word - 1;
                if (pos < CAPU) ulist[rr][pos] = (uint16_t)(base + b);
                ++pos;
            }
        }
        if (lane == 0) ucnt[rr] = (total < CAPU) ? total : CAPU;
    }
    __syncthreads();
    // Stage C: A_meta emission (stores drain while stage B gathers)
    for (int c = 0; c < 5; ++c) {
        int j4 = 4 * (t + 256 * c);
        if (j4 >= N_NODES) break;
        int w = j4 >> 5, sh = j4 & 31;
        const float4* bp = (const float4*)(b4 + (size_t)j4 * 4);
        float4 bj0 = bp[0], bj1 = bp[1], bj2 = bp[2], bj3 = bp[3];
        #pragma unroll
        for (int r = 0; r < 8; ++r) {
            uint32_t q0 = pw[0][r][w] >> sh;
            uint32_t q1 = pw[1][r][w] >> sh;
            uint32_t q2 = pw[2][r][w] >> sh;
            uint32_t un = (q0 | q1 | q2) & 0xFu;
            float4 outv = make_float4(0.f, 0.f, 0.f, 0.f);
            if (un) {
                float A0 = a_s[r][0], A1 = a_s[r][1], A2 = a_s[r][2];
                if (un & 1u) outv.x = attn_frac(A0 + bj0.x, A1 + bj0.y, A2 + bj0.z, q0 & 1u, q1 & 1u, q2 & 1u);
                if (un & 2u) outv.y = attn_frac(A0 + bj1.x, A1 + bj1.y, A2 + bj1.z, q0 & 2u, q1 & 2u, q2 & 2u);
                if (un & 4u) outv.z = attn_frac(A0 + bj2.x, A1 + bj2.y, A2 + bj2.z, q0 & 4u, q1 & 4u, q2 & 4u);
                if (un & 8u) outv.w = attn_frac(A0 + bj3.x, A1 + bj3.y, A2 + bj3.z, q0 & 8u, q1 & 8u, q2 & 8u);
            }
            *(float4*)(Am + (size_t)(i0 + r) * N_NODES + j4) = outv;
        }
    }
    // Stage B: predictions; thread = (row r = t>>5, c-lane c0 = t&31)
    {
        int r = t >> 5;
        int c0 = t & 31;
        int i = i0 + r;
        bool has4 = (c0 < 4);
        const float* gself = Gd + (size_t)i * NCLS;
        float s0 = gself[c0], s1 = gself[c0 + 32], s2 = gself[c0 + 64];
        float s3 = has4 ? gself[c0 + 96] : 0.f;
        int nn = ucnt[r];
        for (int n = 0; n < nn; ++n) {
            const float* g = Gd + (size_t)ulist[r][n] * NCLS;
            s0 += g[c0];
            s1 += g[c0 + 32];
            s2 += g[c0 + 64];
            if (has4) s3 += g[c0 + 96];
        }
        float ud = udinv[i];
        float* pr = pred + (size_t)i * NCLS;
        pr[c0]      = ud * s0 + bf[c0];
        pr[c0 + 32] = ud * s1 + bf[c0 + 32];
        pr[c0 + 64] = ud * s2 + bf[c0 + 64];
        if (has4) pr[c0 + 96] = ud * s3 + bf[c0 + 96];
    }
}

extern "C" void kernel_launch(void* const* d_in, const int* in_sizes, int n_in,
                              void* d_out, int out_size, void* d_ws, size_t ws_size,
                              hipStream_t stream) {
    const float* feat = (const float*)d_in[0];
    const float* adj  = (const float*)d_in[1];
    const float* Wg   = (const float*)d_in[2];
    const float* bg   = (const float*)d_in[3];
    const float* aw   = (const float*)d_in[4];
    const float* Wf   = (const float*)d_in[5];
    const float* bf   = (const float*)d_in[6];

    float* f_meta = (float*)d_out;
    float* Am     = f_meta + (size_t)N_NODES * DOUT;
    float* pred   = Am + (size_t)N_NODES * N_NODES;

    char* ws = (char*)d_ws;
    size_t off = 0;
    auto alloc = [&](size_t bytes) {
        void* p = ws + off;
        off = (off + bytes + 255) & ~(size_t)255;
        return p;
    };
    uint32_t* planes = (uint32_t*)alloc((size_t)KMP * N_NODES * WSTRIDE * 4);
    float* dinv  = (float*)alloc((size_t)KMP * N_NODES * 4);
    float* Wt    = (float*)alloc((size_t)KMP * DOUT * DIN * 4);
    float* XWd   = (float*)alloc((size_t)KMP * N_NODES * DOUT * 4);
    float* a4    = (float*)alloc((size_t)N_NODES * 16);
    float* b4    = (float*)alloc((size_t)N_NODES * 16);
    float* udinv = (float*)alloc((size_t)N_NODES * 4);
    float* Gd    = (float*)alloc((size_t)N_NODES * NCLS * 4);
    uint16_t* nbrK = (uint16_t*)alloc((size_t)KMP * N_NODES * CAPK * 2);
    int*      cntK = (int*)alloc((size_t)KMP * N_NODES * 4);

    hipLaunchKernelGGL(k1_bits_deg_nbr, dim3(KMP * N_NODES), dim3(256), 0, stream,
                       adj, planes, dinv, nbrK, cntK);
    hipLaunchKernelGGL(k_udinv, dim3(N_NODES), dim3(64), 0, stream, planes, udinv);
    hipLaunchKernelGGL(k2a_wt, dim3((KMP * DIN * DOUT + 255) / 256), dim3(256), 0, stream, Wg, Wt);
    hipLaunchKernelGGL(k2b_xwd, dim3((N_NODES * DOUT + 255) / 256), dim3(256), 0, stream,
                       feat, Wt, dinv, XWd);
    hipLaunchKernelGGL(k34_fmeta_ab_gd, dim3(N_NODES / 4), dim3(64), 0, stream,
                       nbrK, cntK, XWd, dinv, bg, aw, Wf, udinv, f_meta, a4, b4, Gd);
    hipLaunchKernelGGL(k58_ameta_pred, dim3(N_NODES / 8), dim3(256), 0, stream,
                       planes, a4, b4, Gd, udinv, bf, Am, pred);
}

// Round 6
// 633.413 us; speedup vs baseline: 1.0204x; 1.0204x over previous
//
#include <hip/hip_runtime.h>
#include <hip/hip_bf16.h>
#include <cstdint>
#include <cstddef>

#define N_NODES 5000
#define DIN 512
#define DOUT 16
#define KMP 3
#define NCLS 100
#define WSTRIDE 160   // u32 words per bit-row (157 used, padded)
#define NWORDS 157    // ceil(5000/32)
#define NQ 1250       // float4 groups per row
#define CAPK 160      // per-plane neighbor list capacity (deg ~64±8)
#define CAPU 320      // union list capacity (deg ~189±14)

// ---- K1: adj -> bit planes + degree rsqrt + per-plane neighbor lists ------
// block 256, one block per row (row = k*5000+i); float4 loads, nibble-pack
// in LDS, block-scan for list offsets.
__global__ void k1_bits_deg_nbr(const float* __restrict__ adj,
                                uint32_t* __restrict__ planes,
                                float* __restrict__ dinv,
                                uint16_t* __restrict__ nbrK,
                                int* __restrict__ cntK) {
    int row = blockIdx.x;
    int t   = threadIdx.x;
    int lane = t & 63;
    int wv   = t >> 6;
    const float* arow = adj + (size_t)row * N_NODES;
    __shared__ uint32_t nib32[320];       // 1280 nibble bytes
    __shared__ int wtot[4];
    uint8_t* nib = (uint8_t*)nib32;
    #pragma unroll
    for (int it = 0; it < 5; ++it) {
        int q = it * 256 + t;             // q < 1280
        uint32_t m = 0;
        if (q < NQ) {
            float4 v = *(const float4*)(arow + 4 * q);
            m = (v.x != 0.f ? 1u : 0u) | (v.y != 0.f ? 2u : 0u) |
                (v.z != 0.f ? 4u : 0u) | (v.w != 0.f ? 8u : 0u);
        }
        nib[q] = (uint8_t)m;
    }
    __syncthreads();
    uint32_t word = 0;
    int cnt = 0;
    if (t < NWORDS) {
        uint32_t lo = nib32[2 * t], hi = nib32[2 * t + 1];
        word = (lo & 0xFu) | ((lo >> 4) & 0xF0u) | ((lo >> 8) & 0xF00u) | ((lo >> 12) & 0xF000u)
             | ((hi << 16) & 0xF0000u) | ((hi << 12) & 0xF00000u)
             | ((hi << 8) & 0xF000000u) | ((hi << 4) & 0xF0000000u);
        planes[(size_t)row * WSTRIDE + t] = word;
        cnt = __popc(word);
    }
    // wave inclusive scan of popcounts
    int x = cnt;
    #pragma unroll
    for (int s = 1; s < 64; s <<= 1) {
        int y = __shfl_up(x, s);
        if (lane >= s) x += y;
    }
    if (lane == 63) wtot[wv] = x;
    __syncthreads();
    int prefix = 0;
    #pragma unroll
    for (int w = 0; w < 4; ++w) if (w < wv) prefix += wtot[w];
    int total = wtot[0] + wtot[1] + wtot[2] + wtot[3];
    int pos = prefix + x - cnt;           // block-exclusive offset of this word's bits
    uint16_t* out = nbrK + (size_t)row * CAPK;
    while (word) {
        int b = __builtin_ctz(word);
        word &= word - 1;
        if (pos < CAPK) out[pos] = (uint16_t)(32 * t + b);
        ++pos;
    }
    if (t == 0) {
        dinv[row] = rsqrtf(1.0f + (float)total);
        cntK[row] = (total < CAPK) ? total : CAPK;
    }
}

// ------- K1b: union neighbor list + udinv, wave per row (5000 blocks) ------
__global__ void k_union(const uint32_t* __restrict__ planes,
                        uint16_t* __restrict__ nbrU, int* __restrict__ cntU,
                        float* __restrict__ udinv) {
    int i = blockIdx.x;
    int lane = threadIdx.x;  // 64
    const uint32_t* p0 = planes + (size_t)i * WSTRIDE;
    const uint32_t* p1 = planes + (size_t)(N_NODES + i) * WSTRIDE;
    const uint32_t* p2 = planes + (size_t)(2 * N_NODES + i) * WSTRIDE;
    uint32_t w0 = p0[lane] | p1[lane] | p2[lane];
    uint32_t w1 = p0[lane + 64] | p1[lane + 64] | p2[lane + 64];
    uint32_t w2 = 0;
    if (lane + 128 < NWORDS) w2 = p0[lane + 128] | p1[lane + 128] | p2[lane + 128];
    int cnt = __popc(w0) + __popc(w1) + __popc(w2);
    int x = cnt;
    #pragma unroll
    for (int s = 1; s < 64; s <<= 1) {
        int y = __shfl_up(x, s);
        if (lane >= s) x += y;
    }
    int pos = x - cnt;
    int total = __shfl(x, 63);
    uint16_t* out = nbrU + (size_t)i * CAPU;
    uint32_t ws[3] = {w0, w1, w2};
    #pragma unroll
    for (int p = 0; p < 3; ++p) {
        uint32_t word = ws[p];
        int base = 32 * (lane + 64 * p);
        while (word) {
            int b = __builtin_ctz(word);
            word &= word - 1;
            if (pos < CAPU) out[pos] = (uint16_t)(base + b);
            ++pos;
        }
    }
    if (lane == 0) {
        cntU[i] = (total < CAPU) ? total : CAPU;
        udinv[i] = rsqrtf(1.0f + (float)total);
    }
}

// ---------------- K2a: transpose W_gnn -> Wt[k][o][d] ----------------
__global__ void k2a_wt(const float* __restrict__ W, float* __restrict__ Wt) {
    int t = blockIdx.x * blockDim.x + threadIdx.x;
    if (t >= KMP * DIN * DOUT) return;
    int d = t % DIN; int rest = t / DIN; int o = rest % DOUT; int k = rest / DOUT;
    Wt[t] = W[((size_t)k * DIN + d) * DOUT + o];
}

// -------- K2b: XWd[k][j][o] = dinv[k][j]*(feat[j].Wt[k][o]), k folded ------
__global__ void k2b_xwd(const float* __restrict__ feat, const float* __restrict__ Wt,
                        const float* __restrict__ dinv, float* __restrict__ XWd) {
    int t = blockIdx.x * blockDim.x + threadIdx.x;
    if (t >= N_NODES * DOUT) return;
    int o = t & 15; int j = t >> 4;
    const float4* f4 = (const float4*)(feat + (size_t)j * DIN);
    const float4* w0 = (const float4*)(Wt + (size_t)(0 * DOUT + o) * DIN);
    const float4* w1 = (const float4*)(Wt + (size_t)(1 * DOUT + o) * DIN);
    const float4* w2 = (const float4*)(Wt + (size_t)(2 * DOUT + o) * DIN);
    float a0 = 0.f, a1 = 0.f, a2 = 0.f;
    #pragma unroll 2
    for (int d4 = 0; d4 < DIN / 4; ++d4) {
        float4 f = f4[d4];
        float4 b0 = w0[d4], b1 = w1[d4], b2 = w2[d4];
        a0 += f.x * b0.x + f.y * b0.y + f.z * b0.z + f.w * b0.w;
        a1 += f.x * b1.x + f.y * b1.y + f.z * b1.z + f.w * b1.w;
        a2 += f.x * b2.x + f.y * b2.y + f.z * b2.z + f.w * b2.w;
    }
    XWd[(size_t)(0 * N_NODES + j) * DOUT + o] = a0 * dinv[0 * N_NODES + j];
    XWd[(size_t)(1 * N_NODES + j) * DOUT + o] = a1 * dinv[1 * N_NODES + j];
    XWd[(size_t)(2 * N_NODES + j) * DOUT + o] = a2 * dinv[2 * N_NODES + j];
}

// ---- K34: sparse h + max -> f_meta, attention coeffs a4/b4, and Gd --------
// block 64 = 4 groups of 16 lanes; group = row i, lane = o; grid 1250
__global__ void k34_fmeta_ab_gd(const uint16_t* __restrict__ nbrK, const int* __restrict__ cntK,
                                const float* __restrict__ XWd, const float* __restrict__ dinv,
                                const float* __restrict__ bg, const float* __restrict__ aw,
                                const float* __restrict__ Wf, const float* __restrict__ udinv,
                                float* __restrict__ f_meta, float* __restrict__ a4,
                                float* __restrict__ b4, float* __restrict__ Gd) {
    int t = threadIdx.x;
    int o = t & 15;
    int r = t >> 4;                 // group 0..3
    int i = blockIdx.x * 4 + r;
    __shared__ float fs[4][17];
    float hmax = -1e30f;
    #pragma unroll
    for (int k = 0; k < KMP; ++k) {
        const float* xw = XWd + (size_t)k * N_NODES * DOUT;
        int row = k * N_NODES + i;
        int nn = cntK[row];
        const uint16_t* nb = nbrK + (size_t)row * CAPK;
        float a0 = xw[i * DOUT + o];   // self-loop (diag double-count matches Ahat)
        float a1 = 0.f, a2 = 0.f, a3 = 0.f;
        int n = 0;
        for (; n + 4 <= nn; n += 4) {
            ushort4 jj = *(const ushort4*)(nb + n);
            a0 += xw[(int)jj.x * DOUT + o];
            a1 += xw[(int)jj.y * DOUT + o];
            a2 += xw[(int)jj.z * DOUT + o];
            a3 += xw[(int)jj.w * DOUT + o];
        }
        for (; n < nn; ++n) a0 += xw[(int)nb[n] * DOUT + o];
        float h = dinv[row] * ((a0 + a1) + (a2 + a3)) + bg[k * DOUT + o];
        hmax = fmaxf(hmax, h);
    }
    f_meta[i * DOUT + o] = hmax;
    fs[r][o] = hmax;
    // attention coefficients via 16-wide reduction (group-local)
    float sa0 = hmax * aw[0 * 32 + o], sb0 = hmax * aw[0 * 32 + 16 + o];
    float sa1 = hmax * aw[1 * 32 + o], sb1 = hmax * aw[1 * 32 + 16 + o];
    float sa2 = hmax * aw[2 * 32 + o], sb2 = hmax * aw[2 * 32 + 16 + o];
    #pragma unroll
    for (int s = 1; s < 16; s <<= 1) {
        sa0 += __shfl_xor(sa0, s, 16); sb0 += __shfl_xor(sb0, s, 16);
        sa1 += __shfl_xor(sa1, s, 16); sb1 += __shfl_xor(sb1, s, 16);
        sa2 += __shfl_xor(sa2, s, 16); sb2 += __shfl_xor(sb2, s, 16);
    }
    if (o < 4) {
        float sa = (o == 0) ? sa0 : (o == 1) ? sa1 : (o == 2) ? sa2 : 0.f;
        float sb = (o == 0) ? sb0 : (o == 1) ? sb1 : (o == 2) ? sb2 : 0.f;
        a4[i * 4 + o] = sa;
        b4[i * 4 + o] = sb;
    }
    __syncthreads();
    // Gd[i][c] = udinv[i] * (f_meta[i] . W_final[:,c]); 16 lanes cover 100 c's
    float f[DOUT];
    #pragma unroll
    for (int q = 0; q < DOUT; ++q) f[q] = fs[r][q];
    float ud = udinv[i];
    for (int c = o; c < NCLS; c += 16) {
        float acc = 0.f;
        #pragma unroll
        for (int q = 0; q < DOUT; ++q) acc += f[q] * Wf[q * NCLS + c];
        Gd[(size_t)i * NCLS + c] = acc * ud;
    }
}

// ------- K5: dense A_meta from bits + softmax-over-k, float4 stores --------
__device__ __forceinline__ float attn_frac(float x0, float x1, float x2,
                                           uint32_t b0, uint32_t b1, uint32_t b2) {
    float e0 = __expf(fmaxf(x0, 0.f));
    float e1 = __expf(fmaxf(x1, 0.f));
    float e2 = __expf(fmaxf(x2, 0.f));
    float num = (b0 ? e0 : 0.f) + (b1 ? e1 : 0.f) + (b2 ? e2 : 0.f);
    return __fdividef(num, e0 + e1 + e2);
}

__global__ void k5_ameta(const uint32_t* __restrict__ planes,
                         const float* __restrict__ a4, const float* __restrict__ b4,
                         float* __restrict__ Am) {
    int i0 = blockIdx.x * 8;
    int t = threadIdx.x;
    __shared__ float a_s[8][3];
    if (t < 24) { int r = t / 3, k = t % 3; a_s[r][k] = a4[(i0 + r) * 4 + k]; }
    __syncthreads();
    for (int c = 0; c < 5; ++c) {
        int j4 = 4 * (t + 256 * c);
        if (j4 >= N_NODES) break;
        int w = j4 >> 5, sh = j4 & 31;
        const float4* bp = (const float4*)(b4 + (size_t)j4 * 4);
        float4 bj0 = bp[0], bj1 = bp[1], bj2 = bp[2], bj3 = bp[3];
        #pragma unroll
        for (int r = 0; r < 8; ++r) {
            int i = i0 + r;
            uint32_t q0 = planes[(size_t)i * WSTRIDE + w] >> sh;
            uint32_t q1 = planes[(size_t)(N_NODES + i) * WSTRIDE + w] >> sh;
            uint32_t q2 = planes[(size_t)(2 * N_NODES + i) * WSTRIDE + w] >> sh;
            uint32_t un = (q0 | q1 | q2) & 0xFu;
            float4 out = make_float4(0.f, 0.f, 0.f, 0.f);
            if (un) {
                float A0 = a_s[r][0], A1 = a_s[r][1], A2 = a_s[r][2];
                if (un & 1u) out.x = attn_frac(A0 + bj0.x, A1 + bj0.y, A2 + bj0.z, q0 & 1u, q1 & 1u, q2 & 1u);
                if (un & 2u) out.y = attn_frac(A0 + bj1.x, A1 + bj1.y, A2 + bj1.z, q0 & 2u, q1 & 2u, q2 & 2u);
                if (un & 4u) out.z = attn_frac(A0 + bj2.x, A1 + bj2.y, A2 + bj2.z, q0 & 4u, q1 & 4u, q2 & 4u);
                if (un & 8u) out.w = attn_frac(A0 + bj3.x, A1 + bj3.y, A2 + bj3.z, q0 & 8u, q1 & 8u, q2 & 8u);
            }
            *(float4*)(Am + (size_t)i * N_NODES + j4) = out;
        }
    }
}

// ------- K8: predictions = norm_meta SpMM over union list (ILP4) -----------
__global__ void k8_pred(const uint16_t* __restrict__ nbrU, const int* __restrict__ cntU,
                        const float* __restrict__ Gd, const float* __restrict__ udinv,
                        const float* __restrict__ bf, float* __restrict__ pred) {
    int i = blockIdx.x;
    int c = threadIdx.x;  // block 128
    if (c >= NCLS) return;
    int nn = cntU[i];
    const uint16_t* nb = nbrU + (size_t)i * CAPU;
    float a0 = Gd[(size_t)i * NCLS + c];  // self-loop
    float a1 = 0.f, a2 = 0.f, a3 = 0.f;
    int n = 0;
    for (; n + 4 <= nn; n += 4) {
        ushort4 jj = *(const ushort4*)(nb + n);
        a0 += Gd[(size_t)jj.x * NCLS + c];
        a1 += Gd[(size_t)jj.y * NCLS + c];
        a2 += Gd[(size_t)jj.z * NCLS + c];
        a3 += Gd[(size_t)jj.w * NCLS + c];
    }
    for (; n < nn; ++n) a0 += Gd[(size_t)nb[n] * NCLS + c];
    pred[(size_t)i * NCLS + c] = udinv[i] * ((a0 + a1) + (a2 + a3)) + bf[c];
}

extern "C" void kernel_launch(void* const* d_in, const int* in_sizes, int n_in,
                              void* d_out, int out_size, void* d_ws, size_t ws_size,
                              hipStream_t stream) {
    const float* feat = (const float*)d_in[0];
    const float* adj  = (const float*)d_in[1];
    const float* Wg   = (const float*)d_in[2];
    const float* bg   = (const float*)d_in[3];
    const float* aw   = (const float*)d_in[4];
    const float* Wf   = (const float*)d_in[5];
    const float* bf   = (const float*)d_in[6];

    float* f_meta = (float*)d_out;
    float* Am     = f_meta + (size_t)N_NODES * DOUT;
    float* pred   = Am + (size_t)N_NODES * N_NODES;

    char* ws = (char*)d_ws;
    size_t off = 0;
    auto alloc = [&](size_t bytes) {
        void* p = ws + off;
        off = (off + bytes + 255) & ~(size_t)255;
        return p;
    };
    uint32_t* planes = (uint32_t*)alloc((size_t)KMP * N_NODES * WSTRIDE * 4);
    float* dinv  = (float*)alloc((size_t)KMP * N_NODES * 4);
    float* Wt    = (float*)alloc((size_t)KMP * DOUT * DIN * 4);
    float* XWd   = (float*)alloc((size_t)KMP * N_NODES * DOUT * 4);
    float* a4    = (float*)alloc((size_t)N_NODES * 16);
    float* b4    = (float*)alloc((size_t)N_NODES * 16);
    float* udinv = (float*)alloc((size_t)N_NODES * 4);
    float* Gd    = (float*)alloc((size_t)N_NODES * NCLS * 4);
    uint16_t* nbrK = (uint16_t*)alloc((size_t)KMP * N_NODES * CAPK * 2);
    int*      cntK = (int*)alloc((size_t)KMP * N_NODES * 4);
    uint16_t* nbrU = (uint16_t*)alloc((size_t)N_NODES * CAPU * 2);
    int*      cntU = (int*)alloc((size_t)N_NODES * 4);

    hipLaunchKernelGGL(k1_bits_deg_nbr, dim3(KMP * N_NODES), dim3(256), 0, stream,
                       adj, planes, dinv, nbrK, cntK);
    hipLaunchKernelGGL(k_union, dim3(N_NODES), dim3(64), 0, stream,
                       planes, nbrU, cntU, udinv);
    hipLaunchKernelGGL(k2a_wt, dim3((KMP * DIN * DOUT + 255) / 256), dim3(256), 0, stream, Wg, Wt);
    hipLaunchKernelGGL(k2b_xwd, dim3((N_NODES * DOUT + 255) / 256), dim3(256), 0, stream,
                       feat, Wt, dinv, XWd);
    hipLaunchKernelGGL(k34_fmeta_ab_gd, dim3(N_NODES / 4), dim3(64), 0, stream,
                       nbrK, cntK, XWd, dinv, bg, aw, Wf, udinv, f_meta, a4, b4, Gd);
    hipLaunchKernelGGL(k5_ameta, dim3(N_NODES / 8), dim3(256), 0, stream, planes, a4, b4, Am);
    hipLaunchKernelGGL(k8_pred, dim3(N_NODES), dim3(128), 0, stream, nbrU, cntU, Gd, udinv, bf, pred);
}